// Round 2
// baseline (498.984 us; speedup 1.0000x reference)
//
#include <hip/hip_runtime.h>
#include <hip/hip_bf16.h>

#define NPTS 60000
#define CIN  128
#define COUT 128
#define NH   8
#define CH   16
#define KK   27
#define NEDGE 960000
#define CAP  96

// ---------------------------------------------------------------------------
// Shared GEMM tile: 64 points x 128 cols, activations in LDS [64][130] (padded),
// weights in LDS as float4 [128][32]. 256 threads: rg = tid/16 (4 rows each),
// cg = tid%16 (8 cols each). 32 FMA per k-step per thread.
// ---------------------------------------------------------------------------
__device__ __forceinline__ void gemm_tile(const float* __restrict__ hs,
                                          const float4* __restrict__ ws,
                                          int rg, int cg, float acc[4][8]) {
#pragma unroll 4
    for (int k = 0; k < 128; ++k) {
        float4 w0 = ws[k * 32 + cg * 2];
        float4 w1 = ws[k * 32 + cg * 2 + 1];
#pragma unroll
        for (int i = 0; i < 4; ++i) {
            float hv = hs[(rg * 4 + i) * 130 + k];
            acc[i][0] = fmaf(hv, w0.x, acc[i][0]);
            acc[i][1] = fmaf(hv, w0.y, acc[i][1]);
            acc[i][2] = fmaf(hv, w0.z, acc[i][2]);
            acc[i][3] = fmaf(hv, w0.w, acc[i][3]);
            acc[i][4] = fmaf(hv, w1.x, acc[i][4]);
            acc[i][5] = fmaf(hv, w1.y, acc[i][5]);
            acc[i][6] = fmaf(hv, w1.z, acc[i][6]);
            acc[i][7] = fmaf(hv, w1.w, acc[i][7]);
        }
    }
}

// ---------------------------------------------------------------------------
// Kernel A: x = feats + (relu2(relu1(np@w1)@w2) @ w3 + b3)
// ---------------------------------------------------------------------------
__global__ __launch_bounds__(256) void mlp_x_kernel(
    const float* __restrict__ feats, const float* __restrict__ npnts,
    const float* __restrict__ w1, const float* __restrict__ bn1s, const float* __restrict__ bn1h,
    const float* __restrict__ w2, const float* __restrict__ bn2s, const float* __restrict__ bn2h,
    const float* __restrict__ w3, const float* __restrict__ b3,
    float* __restrict__ x) {
    __shared__ float4 ws4[128 * 32];
    __shared__ float  h2s[64 * 130];
    __shared__ float  w2s[3 * 128];
    __shared__ float  bn2ss[128], bn2hh[128], b3s[128];
    __shared__ float  w1s[9], bn1ss[3], bn1hh[3];

    const int tid = threadIdx.x;
    const int batch = blockIdx.x;

    const float4* g = (const float4*)w3;
    for (int i = tid; i < 128 * 32; i += 256) ws4[i] = g[i];
    for (int i = tid; i < 384; i += 256) w2s[i] = w2[i];
    if (tid < 128) { bn2ss[tid] = bn2s[tid]; bn2hh[tid] = bn2h[tid]; b3s[tid] = b3[tid]; }
    if (tid < 9) w1s[tid] = w1[tid];
    if (tid < 3) { bn1ss[tid] = bn1s[tid]; bn1hh[tid] = bn1h[tid]; }
    __syncthreads();

    // tiny MLP -> h2 tile (64 points x 128), zero rows past N
    {
        const int p  = tid >> 2;          // 0..63
        const int c0 = (tid & 3) << 5;    // 0,32,64,96
        const int pt = batch * 64 + p;
        const bool valid = pt < NPTS;
        float h1a = 0.f, h1b = 0.f, h1c = 0.f;
        if (valid) {
            float p0 = npnts[pt * 3 + 0], p1 = npnts[pt * 3 + 1], p2 = npnts[pt * 3 + 2];
            float t0 = p0 * w1s[0] + p1 * w1s[3] + p2 * w1s[6];
            float t1 = p0 * w1s[1] + p1 * w1s[4] + p2 * w1s[7];
            float t2 = p0 * w1s[2] + p1 * w1s[5] + p2 * w1s[8];
            h1a = fmaxf(t0 * bn1ss[0] + bn1hh[0], 0.f);
            h1b = fmaxf(t1 * bn1ss[1] + bn1hh[1], 0.f);
            h1c = fmaxf(t2 * bn1ss[2] + bn1hh[2], 0.f);
        }
        for (int c = c0; c < c0 + 32; ++c) {
            float t  = h1a * w2s[c] + h1b * w2s[128 + c] + h1c * w2s[256 + c];
            float hv = fmaxf(t * bn2ss[c] + bn2hh[c], 0.f);
            h2s[p * 130 + c] = valid ? hv : 0.f;
        }
    }
    __syncthreads();

    float acc[4][8] = {};
    const int rg = tid >> 4, cg = tid & 15;
    gemm_tile(h2s, ws4, rg, cg, acc);

    const float4* fv = (const float4*)feats;
    float4* xv = (float4*)x;
#pragma unroll
    for (int i = 0; i < 4; ++i) {
        int pt = batch * 64 + rg * 4 + i;
        if (pt >= NPTS) break;
        int c = cg * 8;
        int vi = (pt * 128 + c) >> 2;
        float4 f0 = fv[vi], f1 = fv[vi + 1];
        float4 o0, o1;
        o0.x = acc[i][0] + b3s[c + 0] + f0.x;
        o0.y = acc[i][1] + b3s[c + 1] + f0.y;
        o0.z = acc[i][2] + b3s[c + 2] + f0.z;
        o0.w = acc[i][3] + b3s[c + 3] + f0.w;
        o1.x = acc[i][4] + b3s[c + 4] + f1.x;
        o1.y = acc[i][5] + b3s[c + 5] + f1.y;
        o1.z = acc[i][6] + b3s[c + 6] + f1.z;
        o1.w = acc[i][7] + b3s[c + 7] + f1.w;
        xv[vi] = o0; xv[vi + 1] = o1;
    }
}

// ---------------------------------------------------------------------------
// Kernel Bq: nq = l2norm_per_head(x @ wq + bq)
// ---------------------------------------------------------------------------
__global__ __launch_bounds__(256) void proj_q_kernel(
    const float* __restrict__ x, const float* __restrict__ wq,
    const float* __restrict__ bq, float* __restrict__ nqout) {
    __shared__ float4 ws4[128 * 32];
    __shared__ float  xs[64 * 130];
    __shared__ float  bqs[128];

    const int tid = threadIdx.x;
    const int batch = blockIdx.x;

    const float4* g = (const float4*)wq;
    for (int i = tid; i < 128 * 32; i += 256) ws4[i] = g[i];
    if (tid < 128) bqs[tid] = bq[tid];
    const float4* xv = (const float4*)x;
    for (int idx = tid; idx < 2048; idx += 256) {
        int row = idx >> 5, c4 = idx & 31;
        int pt = batch * 64 + row;
        float4 val = make_float4(0.f, 0.f, 0.f, 0.f);
        if (pt < NPTS) val = xv[pt * 32 + c4];
        int b = row * 130 + c4 * 4;
        xs[b] = val.x; xs[b + 1] = val.y; xs[b + 2] = val.z; xs[b + 3] = val.w;
    }
    __syncthreads();

    float acc[4][8] = {};
    const int rg = tid >> 4, cg = tid & 15;
    gemm_tile(xs, ws4, rg, cg, acc);

    float4* outv = (float4*)nqout;
#pragma unroll
    for (int i = 0; i < 4; ++i) {
        int pt = batch * 64 + rg * 4 + i;
        int c = cg * 8;
        float qv[8]; float ss = 0.f;
#pragma unroll
        for (int j = 0; j < 8; ++j) { qv[j] = acc[i][j] + bqs[c + j]; ss += qv[j] * qv[j]; }
        ss += __shfl_xor(ss, 1);   // partner thread covers other half of this head
        float inv = 1.f / fmaxf(sqrtf(ss), 1e-12f);
        if (pt < NPTS) {
            int vi = (pt * 128 + c) >> 2;
            outv[vi]     = make_float4(qv[0] * inv, qv[1] * inv, qv[2] * inv, qv[3] * inv);
            outv[vi + 1] = make_float4(qv[4] * inv, qv[5] * inv, qv[6] * inv, qv[7] * inv);
        }
    }
}

// ---------------------------------------------------------------------------
// Generic projection: out = in @ w + b   (used for v and the final wo GEMM)
// ---------------------------------------------------------------------------
__global__ __launch_bounds__(256) void proj_kernel(
    const float* __restrict__ in, const float* __restrict__ w,
    const float* __restrict__ b, float* __restrict__ out) {
    __shared__ float4 ws4[128 * 32];
    __shared__ float  xs[64 * 130];
    __shared__ float  bs[128];

    const int tid = threadIdx.x;
    const int batch = blockIdx.x;

    const float4* g = (const float4*)w;
    for (int i = tid; i < 128 * 32; i += 256) ws4[i] = g[i];
    if (tid < 128) bs[tid] = b[tid];
    const float4* xv = (const float4*)in;
    for (int idx = tid; idx < 2048; idx += 256) {
        int row = idx >> 5, c4 = idx & 31;
        int pt = batch * 64 + row;
        float4 val = make_float4(0.f, 0.f, 0.f, 0.f);
        if (pt < NPTS) val = xv[pt * 32 + c4];
        int bo = row * 130 + c4 * 4;
        xs[bo] = val.x; xs[bo + 1] = val.y; xs[bo + 2] = val.z; xs[bo + 3] = val.w;
    }
    __syncthreads();

    float acc[4][8] = {};
    const int rg = tid >> 4, cg = tid & 15;
    gemm_tile(xs, ws4, rg, cg, acc);

    float4* outv = (float4*)out;
#pragma unroll
    for (int i = 0; i < 4; ++i) {
        int pt = batch * 64 + rg * 4 + i;
        if (pt >= NPTS) break;
        int c = cg * 8;
        int vi = (pt * 128 + c) >> 2;
        outv[vi]     = make_float4(acc[i][0] + bs[c + 0], acc[i][1] + bs[c + 1],
                                   acc[i][2] + bs[c + 2], acc[i][3] + bs[c + 3]);
        outv[vi + 1] = make_float4(acc[i][4] + bs[c + 4], acc[i][5] + bs[c + 5],
                                   acc[i][6] + bs[c + 6], acc[i][7] + bs[c + 7]);
    }
}

// ---------------------------------------------------------------------------
// CSR-ish bucketing: zero counts, then scatter edges into per-query buckets.
// Packed record: (key_idx << 5) | kernel_offset  (key<65536, koff<32)
// NOTE: index arrays arrive as int32 (harness converts integer inputs).
// ---------------------------------------------------------------------------
__global__ __launch_bounds__(256) void zero_cnt_kernel(int* __restrict__ cnt) {
    int i = blockIdx.x * 256 + threadIdx.x;
    if (i < NPTS) cnt[i] = 0;
}

__global__ __launch_bounds__(256) void build_buckets_kernel(
    const int* __restrict__ r0, const int* __restrict__ r1,
    int* __restrict__ cnt, int* __restrict__ bucket) {
    int m = blockIdx.x * 256 + threadIdx.x;
    if (m >= NEDGE) return;
    int a = r0[m];
    int q = r1[m];
    if (q < 0 || q >= NPTS) return;              // defensive: never fault
    if (a < 0 || a >= NPTS * KK) return;
    int kidx = a / KK;
    int koff = a - kidx * KK;
    int slot = atomicAdd(&cnt[q], 1);
    if (slot < CAP) bucket[q * CAP + slot] = (kidx << 5) | koff;
}

// ---------------------------------------------------------------------------
// Kernel D: one wave per query. lane l owns output cols l and l+64.
// attn per head = 16-lane shfl_xor reduction; v gathered coalesced.
// ---------------------------------------------------------------------------
__global__ __launch_bounds__(256) void attn_scatter_kernel(
    const float* __restrict__ nq, const float* __restrict__ v,
    const float* __restrict__ pos_enc, const int* __restrict__ cnt,
    const int* __restrict__ bucket, float* __restrict__ pre) {
    __shared__ float nps[KK * 128];

    const int tid = threadIdx.x;
    if (tid < KK * NH) {                 // 216 (k,h) groups, normalize over 16 ch
        int base = tid * 16;
        float val[16]; float ss = 0.f;
#pragma unroll
        for (int i = 0; i < 16; ++i) { val[i] = pos_enc[base + i]; ss += val[i] * val[i]; }
        float inv = 1.f / fmaxf(sqrtf(ss), 1e-12f);
#pragma unroll
        for (int i = 0; i < 16; ++i) nps[base + i] = val[i] * inv;
    }
    __syncthreads();

    const int l = tid & 63;
    const int wid = blockIdx.x * 4 + (tid >> 6);
    const int nwaves = gridDim.x * 4;

    for (int n = wid; n < NPTS; n += nwaves) {
        float nq0 = nq[n * 128 + l];
        float nq1 = nq[n * 128 + 64 + l];
        int deg = min(cnt[n], CAP);
        int base = n * CAP;
        float acc0 = 0.f, acc1 = 0.f;
        for (int e = 0; e < deg; ++e) {
            int rec  = bucket[base + e];
            int koff = rec & 31;
            int kidx = rec >> 5;
            float a0 = nq0 * nps[koff * 128 + l];
            float a1 = nq1 * nps[koff * 128 + 64 + l];
            a0 += __shfl_xor(a0, 1);  a1 += __shfl_xor(a1, 1);
            a0 += __shfl_xor(a0, 2);  a1 += __shfl_xor(a1, 2);
            a0 += __shfl_xor(a0, 4);  a1 += __shfl_xor(a1, 4);
            a0 += __shfl_xor(a0, 8);  a1 += __shfl_xor(a1, 8);
            acc0 = fmaf(a0, v[kidx * 128 + l], acc0);
            acc1 = fmaf(a1, v[kidx * 128 + 64 + l], acc1);
        }
        pre[n * 128 + l] = acc0;
        pre[n * 128 + 64 + l] = acc1;
    }
}

// ---------------------------------------------------------------------------
extern "C" void kernel_launch(void* const* d_in, const int* in_sizes, int n_in,
                              void* d_out, int out_size, void* d_ws, size_t ws_size,
                              hipStream_t stream) {
    const float* feats  = (const float*)d_in[0];
    const float* npnts  = (const float*)d_in[1];
    const float* w1     = (const float*)d_in[2];
    const float* bn1s   = (const float*)d_in[3];
    const float* bn1h   = (const float*)d_in[4];
    const float* w2     = (const float*)d_in[5];
    const float* bn2s   = (const float*)d_in[6];
    const float* bn2h   = (const float*)d_in[7];
    const float* w3     = (const float*)d_in[8];
    const float* b3     = (const float*)d_in[9];
    const float* wq     = (const float*)d_in[10];
    const float* bq     = (const float*)d_in[11];
    const float* wv     = (const float*)d_in[12];
    const float* bv     = (const float*)d_in[13];
    const float* wo     = (const float*)d_in[14];
    const float* bo     = (const float*)d_in[15];
    const float* pos    = (const float*)d_in[16];
    const int*   r0     = (const int*)d_in[17];
    const int*   r1     = (const int*)d_in[18];
    float* out = (float*)d_out;

    // workspace layout (pre aliases x: x is dead before pre is written)
    float* xbuf  = (float*)d_ws;
    float* nqbuf = xbuf + (size_t)NPTS * 128;
    float* vbuf  = nqbuf + (size_t)NPTS * 128;
    float* prebuf = xbuf;                       // alias
    int*   cnt    = (int*)(vbuf + (size_t)NPTS * 128);
    int*   bucket = cnt + NPTS;

    dim3 blk(256);
    const int nbatch = (NPTS + 63) / 64;        // 938

    mlp_x_kernel<<<nbatch, blk, 0, stream>>>(feats, npnts, w1, bn1s, bn1h,
                                             w2, bn2s, bn2h, w3, b3, xbuf);
    proj_q_kernel<<<nbatch, blk, 0, stream>>>(xbuf, wq, bq, nqbuf);
    proj_kernel<<<nbatch, blk, 0, stream>>>(xbuf, wv, bv, vbuf);
    zero_cnt_kernel<<<(NPTS + 255) / 256, blk, 0, stream>>>(cnt);
    build_buckets_kernel<<<(NEDGE + 255) / 256, blk, 0, stream>>>(r0, r1, cnt, bucket);
    attn_scatter_kernel<<<2048, blk, 0, stream>>>(nqbuf, vbuf, pos, cnt, bucket, prebuf);
    proj_kernel<<<nbatch, blk, 0, stream>>>(prebuf, wo, bo, out);
}

// Round 4
// 381.386 us; speedup vs baseline: 1.3083x; 1.3083x over previous
//
#include <hip/hip_runtime.h>
#include <hip/hip_bf16.h>

#define NPTS  60000
#define KK    27
#define NEDGE 960000
#define CAP   96

// ---------------------------------------------------------------------------
// tiny MLP: h2 = relu(bn2(relu(bn1(np@w1)) @ w2))  -> global [N][128]
// ---------------------------------------------------------------------------
__global__ __launch_bounds__(256) void tiny_mlp_kernel(
    const float* __restrict__ npnts,
    const float* __restrict__ w1, const float* __restrict__ bn1s, const float* __restrict__ bn1h,
    const float* __restrict__ w2, const float* __restrict__ bn2s, const float* __restrict__ bn2h,
    float* __restrict__ h2out) {
    __shared__ float w2s[3 * 128];
    __shared__ float sc2[128], sh2[128];
    __shared__ float w1s[9], sc1[3], sh1[3];
    __shared__ float h2s[64 * 129];

    const int tid = threadIdx.x;
    for (int i = tid; i < 384; i += 256) w2s[i] = w2[i];
    if (tid < 128) { sc2[tid] = bn2s[tid]; sh2[tid] = bn2h[tid]; }
    if (tid < 9) w1s[tid] = w1[tid];
    if (tid < 3) { sc1[tid] = bn1s[tid]; sh1[tid] = bn1h[tid]; }
    __syncthreads();

    const int p  = tid >> 2;            // 0..63 point within tile
    const int cq = (tid & 3) * 32;      // 32-col slice
    const int pt = blockIdx.x * 64 + p;
    float h1a = 0.f, h1b = 0.f, h1c = 0.f;
    if (pt < NPTS) {
        float p0 = npnts[pt * 3 + 0], p1 = npnts[pt * 3 + 1], p2 = npnts[pt * 3 + 2];
        float t0 = p0 * w1s[0] + p1 * w1s[3] + p2 * w1s[6];
        float t1 = p0 * w1s[1] + p1 * w1s[4] + p2 * w1s[7];
        float t2 = p0 * w1s[2] + p1 * w1s[5] + p2 * w1s[8];
        h1a = fmaxf(t0 * sc1[0] + sh1[0], 0.f);
        h1b = fmaxf(t1 * sc1[1] + sh1[1], 0.f);
        h1c = fmaxf(t2 * sc1[2] + sh1[2], 0.f);
    }
    for (int c = cq; c < cq + 32; ++c) {
        float t = h1a * w2s[c] + h1b * w2s[128 + c] + h1c * w2s[256 + c];
        h2s[p * 129 + c] = fmaxf(t * sc2[c] + sh2[c], 0.f);
    }
    __syncthreads();
    for (int i = tid; i < 64 * 128; i += 256) {
        int row = i >> 7, col = i & 127;
        int gr = blockIdx.x * 64 + row;
        if (gr < NPTS) h2out[gr * 128 + col] = h2s[row * 129 + col];
    }
}

// ---------------------------------------------------------------------------
// Generic 128x128 GEMM, k-chunked (BK=32) for occupancy: LDS 34.5 KB -> 4 blk/CU.
// 256 thr: tr=tid/16 (rows tr+16i), tc=tid%16 (cols tc*8..+7). 8x8 thread tile.
// MODE: 0 plain, 1 +residual, 2 per-16col-head l2norm.
// ---------------------------------------------------------------------------
template <int MODE>
__global__ __launch_bounds__(256, 4) void gemm128_kernel(
    const float* __restrict__ in, const float* __restrict__ w,
    const float* __restrict__ bias, const float* __restrict__ resid,
    float* __restrict__ out) {
    __shared__ float xs[128][36];
    __shared__ float ws[32][132];
    const int tid = threadIdx.x;
    const int rb  = blockIdx.x * 128;
    const int tr  = tid >> 4;
    const int tc  = tid & 15;
    const int c0  = tc * 8;

    float acc[8][8];
#pragma unroll
    for (int i = 0; i < 8; ++i)
#pragma unroll
        for (int j = 0; j < 8; ++j) acc[i][j] = 0.f;

    const int srow  = tid >> 3;         // 0..31
    const int skq   = (tid & 7) * 4;    // 0..28
    const int wkrow = tid >> 5;         // 0..7
    const int wcq   = (tid & 31) * 4;

    for (int k0 = 0; k0 < 128; k0 += 32) {
        __syncthreads();
#pragma unroll
        for (int rr = 0; rr < 128; rr += 32) {
            int gr = rb + srow + rr;
            float4 val = make_float4(0.f, 0.f, 0.f, 0.f);
            if (gr < NPTS) val = *(const float4*)&in[gr * 128 + k0 + skq];
            *(float4*)&xs[srow + rr][skq] = val;
        }
#pragma unroll
        for (int kk = 0; kk < 32; kk += 8)
            *(float4*)&ws[wkrow + kk][wcq] = *(const float4*)&w[(k0 + wkrow + kk) * 128 + wcq];
        __syncthreads();
#pragma unroll 2
        for (int k = 0; k < 32; ++k) {
            float4 b0 = *(float4*)&ws[k][c0];
            float4 b1 = *(float4*)&ws[k][c0 + 4];
            float av[8];
#pragma unroll
            for (int i = 0; i < 8; ++i) av[i] = xs[tr + 16 * i][k];
#pragma unroll
            for (int i = 0; i < 8; ++i) {
                acc[i][0] = fmaf(av[i], b0.x, acc[i][0]);
                acc[i][1] = fmaf(av[i], b0.y, acc[i][1]);
                acc[i][2] = fmaf(av[i], b0.z, acc[i][2]);
                acc[i][3] = fmaf(av[i], b0.w, acc[i][3]);
                acc[i][4] = fmaf(av[i], b1.x, acc[i][4]);
                acc[i][5] = fmaf(av[i], b1.y, acc[i][5]);
                acc[i][6] = fmaf(av[i], b1.z, acc[i][6]);
                acc[i][7] = fmaf(av[i], b1.w, acc[i][7]);
            }
        }
    }

    float breg[8];
#pragma unroll
    for (int j = 0; j < 8; ++j) breg[j] = bias[c0 + j];

#pragma unroll
    for (int i = 0; i < 8; ++i) {
        int gr = rb + tr + 16 * i;
        float o[8];
#pragma unroll
        for (int j = 0; j < 8; ++j) o[j] = acc[i][j] + breg[j];
        if (MODE == 1) {
            if (gr < NPTS) {
                float4 f0 = *(const float4*)&resid[gr * 128 + c0];
                float4 f1 = *(const float4*)&resid[gr * 128 + c0 + 4];
                o[0] += f0.x; o[1] += f0.y; o[2] += f0.z; o[3] += f0.w;
                o[4] += f1.x; o[5] += f1.y; o[6] += f1.z; o[7] += f1.w;
            }
        }
        if (MODE == 2) {
            float ss = 0.f;
#pragma unroll
            for (int j = 0; j < 8; ++j) ss += o[j] * o[j];
            ss += __shfl_xor(ss, 1);          // partner lane holds other 8 cols of head
            float inv = 1.f / fmaxf(sqrtf(ss), 1e-12f);
#pragma unroll
            for (int j = 0; j < 8; ++j) o[j] *= inv;
        }
        if (gr < NPTS) {
            float4* op = (float4*)&out[gr * 128 + c0];
            op[0] = make_float4(o[0], o[1], o[2], o[3]);
            op[1] = make_float4(o[4], o[5], o[6], o[7]);
        }
    }
}

// ---------------------------------------------------------------------------
// Bucketing (int32 index inputs). Packed record: (key_idx << 5) | koff
// ---------------------------------------------------------------------------
__global__ __launch_bounds__(256) void zero_cnt_kernel(int* __restrict__ cnt) {
    int i = blockIdx.x * 256 + threadIdx.x;
    if (i < NPTS) cnt[i] = 0;
}

__global__ __launch_bounds__(256) void build_buckets_kernel(
    const int* __restrict__ r0, const int* __restrict__ r1,
    int* __restrict__ cnt, int* __restrict__ bucket) {
    int m = blockIdx.x * 256 + threadIdx.x;
    if (m >= NEDGE) return;
    int a = r0[m];
    int q = r1[m];
    if (q < 0 || q >= NPTS) return;
    if (a < 0 || a >= NPTS * KK) return;
    int kidx = a / KK;
    int koff = a - kidx * KK;
    int slot = atomicAdd(&cnt[q], 1);
    if (slot < CAP) bucket[q * CAP + slot] = (kidx << 5) | koff;
}

// ---------------------------------------------------------------------------
// attn+scatter: one wave per query. Lane l owns channels 2l,2l+1 (head l/8).
// Bucket records pre-loaded lane-parallel, extracted via shfl; 4x edge unroll.
// ---------------------------------------------------------------------------
__global__ __launch_bounds__(256, 8) void attn_scatter_kernel(
    const float* __restrict__ nq, const float* __restrict__ v,
    const float* __restrict__ pos_enc, const int* __restrict__ cnt,
    const int* __restrict__ bucket, float* __restrict__ pre) {
    __shared__ float nps[KK * 128];

    const int tid = threadIdx.x;
    if (tid < KK * 8) {                  // 216 (koff,h) groups
        const float4* pv = (const float4*)&pos_enc[tid * 16];
        float4 a = pv[0], b = pv[1], c = pv[2], d = pv[3];
        float ss = a.x*a.x + a.y*a.y + a.z*a.z + a.w*a.w
                 + b.x*b.x + b.y*b.y + b.z*b.z + b.w*b.w
                 + c.x*c.x + c.y*c.y + c.z*c.z + c.w*c.w
                 + d.x*d.x + d.y*d.y + d.z*d.z + d.w*d.w;
        float inv = 1.f / fmaxf(sqrtf(ss), 1e-12f);
        float4* o = (float4*)&nps[tid * 16];
        o[0] = make_float4(a.x*inv, a.y*inv, a.z*inv, a.w*inv);
        o[1] = make_float4(b.x*inv, b.y*inv, b.z*inv, b.w*inv);
        o[2] = make_float4(c.x*inv, c.y*inv, c.z*inv, c.w*inv);
        o[3] = make_float4(d.x*inv, d.y*inv, d.z*inv, d.w*inv);
    }
    __syncthreads();

    const int l = tid & 63;
    const int wid = blockIdx.x * 4 + (tid >> 6);
    const int nwaves = gridDim.x * 4;

#define ATT_EDGE(REC) do {                                                  \
        int koff_ = (REC) & 31; int kidx_ = (REC) >> 5;                     \
        float2 np_ = *(const float2*)&nps[koff_ * 128 + 2 * l];             \
        float2 v_  = *(const float2*)&v[kidx_ * 128 + 2 * l];               \
        float a_ = nq2.x * np_.x + nq2.y * np_.y;                           \
        a_ += __shfl_xor(a_, 1); a_ += __shfl_xor(a_, 2);                   \
        a_ += __shfl_xor(a_, 4);                                            \
        accx = fmaf(a_, v_.x, accx); accy = fmaf(a_, v_.y, accy);           \
    } while (0)

    for (int n = wid; n < NPTS; n += nwaves) {
        float2 nq2 = *(const float2*)&nq[n * 128 + 2 * l];
        int deg = min(cnt[n], CAP);
        int base = n * CAP;
        int myrec = (l < deg) ? bucket[base + l] : 0;
        float accx = 0.f, accy = 0.f;
        int dmain = min(deg, 64);
        int e = 0;
        for (; e + 4 <= dmain; e += 4) {
            int r0 = __shfl(myrec, e);
            int r1 = __shfl(myrec, e + 1);
            int r2 = __shfl(myrec, e + 2);
            int r3 = __shfl(myrec, e + 3);
            ATT_EDGE(r0); ATT_EDGE(r1); ATT_EDGE(r2); ATT_EDGE(r3);
        }
        for (; e < dmain; ++e) {
            int r = __shfl(myrec, e);
            ATT_EDGE(r);
        }
        for (; e < deg; ++e) {           // deg > 64: essentially never
            int r = bucket[base + e];
            ATT_EDGE(r);
        }
        *(float2*)&pre[n * 128 + 2 * l] = make_float2(accx, accy);
    }
#undef ATT_EDGE
}

// ---------------------------------------------------------------------------
extern "C" void kernel_launch(void* const* d_in, const int* in_sizes, int n_in,
                              void* d_out, int out_size, void* d_ws, size_t ws_size,
                              hipStream_t stream) {
    const float* feats = (const float*)d_in[0];
    const float* npnts = (const float*)d_in[1];
    const float* w1    = (const float*)d_in[2];
    const float* bn1s  = (const float*)d_in[3];
    const float* bn1h  = (const float*)d_in[4];
    const float* w2    = (const float*)d_in[5];
    const float* bn2s  = (const float*)d_in[6];
    const float* bn2h  = (const float*)d_in[7];
    const float* w3    = (const float*)d_in[8];
    const float* b3    = (const float*)d_in[9];
    const float* wq    = (const float*)d_in[10];
    const float* bq    = (const float*)d_in[11];
    const float* wv    = (const float*)d_in[12];
    const float* bv    = (const float*)d_in[13];
    const float* wo    = (const float*)d_in[14];
    const float* bo    = (const float*)d_in[15];
    const float* pos   = (const float*)d_in[16];
    const int*   r0    = (const int*)d_in[17];
    const int*   r1    = (const int*)d_in[18];
    float* out = (float*)d_out;

    // Workspace: 4 regions of NPTS*128 floats (30.72 MB each).
    //   A: h2, later cnt+bucket (23.3 MB fits)   B: x, later pre   C: nq   D: v
    float* h2buf = (float*)d_ws;
    float* xbuf  = h2buf + (size_t)NPTS * 128;
    float* nqbuf = xbuf  + (size_t)NPTS * 128;
    float* vbuf  = nqbuf + (size_t)NPTS * 128;
    float* prebuf = xbuf;                       // alias: x dead after q/v proj
    int*   cnt    = (int*)h2buf;                // alias: h2 dead after x-GEMM
    int*   bucket = cnt + NPTS;

    dim3 blk(256);
    const int nb64  = (NPTS + 63) / 64;     // 938
    const int nb128 = (NPTS + 127) / 128;   // 469

    tiny_mlp_kernel<<<nb64, blk, 0, stream>>>(npnts, w1, bn1s, bn1h, w2, bn2s, bn2h, h2buf);
    gemm128_kernel<1><<<nb128, blk, 0, stream>>>(h2buf, w3, b3, feats, xbuf);
    gemm128_kernel<2><<<nb128, blk, 0, stream>>>(xbuf, wq, bq, nullptr, nqbuf);
    gemm128_kernel<0><<<nb128, blk, 0, stream>>>(xbuf, wv, bv, nullptr, vbuf);
    zero_cnt_kernel<<<(NPTS + 255) / 256, blk, 0, stream>>>(cnt);
    build_buckets_kernel<<<(NEDGE + 255) / 256, blk, 0, stream>>>(r0, r1, cnt, bucket);
    attn_scatter_kernel<<<2048, blk, 0, stream>>>(nqbuf, vbuf, pos, cnt, bucket, prebuf);
    gemm128_kernel<0><<<nb128, blk, 0, stream>>>(prebuf, wo, bo, nullptr, out);
}